// Round 2
// baseline (1533.771 us; speedup 1.0000x reference)
//
#include <hip/hip_runtime.h>
#include <cstdint>
#include <cstddef>

typedef __bf16 bf16;
typedef __attribute__((ext_vector_type(8))) __bf16 bf16x8;
typedef __attribute__((ext_vector_type(4))) float f32x4;

#define B_TOT 8192

// ---------------- async global->LDS (16B per lane) ----------------
__device__ __forceinline__ void gload16(const void* g, void* l) {
  __builtin_amdgcn_global_load_lds(
      (__attribute__((address_space(1))) void*)g,
      (__attribute__((address_space(3))) void*)l, 16, 0, 0);
}

// ---------------- block reduction helper (256 threads, 4 waves) ----------------
__device__ __forceinline__ void block_sum2(float& a, float& b, float* lds8) {
#pragma unroll
  for (int o = 32; o; o >>= 1) {
    a += __shfl_xor(a, o, 64);
    b += __shfl_xor(b, o, 64);
  }
  int w = threadIdx.x >> 6;
  if ((threadIdx.x & 63) == 0) { lds8[w] = a; lds8[4 + w] = b; }
  __syncthreads();
  a = lds8[0] + lds8[1] + lds8[2] + lds8[3];
  b = lds8[4] + lds8[5] + lds8[6] + lds8[7];
  __syncthreads();
}

// ---------------- scan phase 1: per-block exclusive scan of L ----------------
__global__ __launch_bounds__(256) void scan1_kernel(
    const int* __restrict__ mask, int* __restrict__ Lg, int* __restrict__ lbase,
    int* __restrict__ btot, int b0)
{
  __shared__ int ts[256];
  const int t = threadIdx.x;
  const int b = blockIdx.x * 256 + t;
  const int* mp = mask + (long)(b0 + b) * 12;
  int nv = 0;
#pragma unroll
  for (int p = 0; p < 12; ++p) nv += (mp[p] != 0);
  int L = (nv < 11 ? nv : 11) + 1;
  ts[t] = L;
  __syncthreads();
  for (int o = 1; o < 256; o <<= 1) {
    int v = (t >= o) ? ts[t - o] : 0;
    __syncthreads();
    ts[t] += v;
    __syncthreads();
  }
  Lg[b] = L;
  lbase[b] = ts[t] - L;
  if (t == 255) btot[blockIdx.x] = ts[255];
}

// ---------------- scan phase 2: scan of block totals (nb <= 32, trivial) ----------------
__global__ __launch_bounds__(64) void scan2_kernel(
    const int* __restrict__ btot, int* __restrict__ boff, int* __restrict__ meta, int nb)
{
  if (threadIdx.x == 0) {
    int acc = 0;
    for (int i = 0; i < nb; ++i) { int v = btot[i]; boff[i] = acc; acc += v; }
    meta[0] = acc;
  }
}

// ---------------- prep: compact age-sorted gather; zl = [z ; lpool]; fbase ----------------
__global__ __launch_bounds__(256) void prep_kernel(
    const float* __restrict__ z, const float* __restrict__ buf,
    const int* __restrict__ mask, const int* __restrict__ idxs,
    const int* __restrict__ lbase, const int* __restrict__ boff,
    int* __restrict__ fbase, bf16* __restrict__ gseq,
    bf16* __restrict__ zl, int b0, int Bc)
{
  const int bl = blockIdx.x;
  const int b  = b0 + bl;
  __shared__ int ord[12];
  __shared__ int s_nv;
  if (threadIdx.x == 0) {
    int id = idxs[b];
    int nv = 0;
    for (int a = 11; a >= 0; --a) {   // ages descending -> oldest first
      int pos = id - a; if (pos < 0) pos += 12;
      if (mask[b * 12 + pos]) ord[nv++] = pos;
    }
    s_nv = nv;
  }
  const long bs = (long)lbase[bl] + boff[bl >> 8];
  if (threadIdx.x == 0) fbase[bl] = (int)bs;
  __syncthreads();
  const int nv = s_nv;
  const int hg = (nv < 11 ? nv : 11);   // valid rows = hg + 1 (last is zero-row or z)
  const int hl = (nv < 4 ? nv : 4);
  const float ld = 1.0f / (float)(hl + 1);
  for (int c = threadIdx.x; c < 768; c += 256) {
    float zv = z[(long)b * 768 + c];
    zl[(long)bl * 768 + c] = (bf16)zv;
    float ls = 0.0f;
    for (int s = 0; s < hg; ++s) {
      float v = buf[((long)b * 12 + ord[s]) * 768 + c];
      gseq[(bs + s) * 768 + c] = (bf16)v;
      if (s < hl) ls += v;
    }
    gseq[(bs + hg) * 768 + c] = (hg == 11) ? (bf16)zv : (bf16)0.0f;
    if (nv >= 4) ls += zv;
    zl[((long)Bc + bl) * 768 + c] = (bf16)(ls * ld);
  }
}

// ---------------- weight transpose f32(K,N) -> bf16(N,K) ----------------
__global__ __launch_bounds__(256) void transpose_bf16(
    const float* __restrict__ W, bf16* __restrict__ Wt, int K, int N)
{
  __shared__ float tile[32][33];
  int bn = blockIdx.x * 32;
  int bk = blockIdx.y * 32;
  int tx = threadIdx.x & 31;
  int ty0 = threadIdx.x >> 5;
  for (int ty = ty0; ty < 32; ty += 8)
    tile[ty][tx] = W[(long)(bk + ty) * N + bn + tx];
  __syncthreads();
  for (int ty = ty0; ty < 32; ty += 8)
    Wt[(long)(bn + ty) * K + bk + tx] = (bf16)tile[tx][ty];
}

__global__ __launch_bounds__(256) void pack3_kernel(
    const float* __restrict__ a, const float* __restrict__ b,
    const float* __restrict__ c, float* __restrict__ out)
{
  int t = blockIdx.x * blockDim.x + threadIdx.x;
  if (t < 768) out[t] = a[t];
  else if (t < 1536) out[t] = b[t - 768];
  else if (t < 2304) out[t] = c[t - 1536];
}

// ---------------- MFMA GEMM 256x256, 8-wave, ksub-slot ring pipeline ----------------
// C(M,N) = A(M,K) @ Bt(N,K)^T + bias. K consumed in 32-wide ksubs; LDS = ring of 4
// A-slots + 4 B-slots (16KB each, 128 KiB total), staged 3 slots ahead via
// global_load_lds with counted s_waitcnt vmcnt(8) at each slot entry (never 0).
// In-slot swizzle: stored 16B-chunk c' = c ^ ((row>>1)&3)  (inverse applied on the
// per-lane global source address; ds_read applies the same XOR) -> each 8-lane octet
// of a ds_read_b128 covers all 8 bank groups (conflict-free).
// Per slot: phase q0 {ds_read A0-3,B0-3 | stage A(s+3) | bar | lgkm0 | prio1 16 MFMA prio0 | bar}
//           phase q1 {ds_read A4-7 (B held) | stage B(s+3) | bar | lgkm0 | prio1 16 MFMA prio0}
// XCD-aware y-swizzle, early-exit past mlim[0] rows, optional row-split B (msplit).
__global__ __launch_bounds__(512, 2) void gemm256(
    const bf16* __restrict__ A, const bf16* __restrict__ Bt,
    const float* __restrict__ bias, void* __restrict__ C,
    int K, int N, int act, int outf32,
    const int* __restrict__ mlim, int msplit,
    const bf16* __restrict__ Bt2, const float* __restrict__ bias2)
{
  __shared__ __align__(16) bf16 smem[65536];   // 128 KiB
  char* sb = (char*)smem;
  int gx = gridDim.x, gy = gridDim.y;
  int bx = blockIdx.x, by = blockIdx.y;
  if ((gy & 7) == 0) {
    int l = bx + gx * by;
    int xcd = l & 7, slot = l >> 3;
    bx = slot % gx;
    by = (slot / gx) * 8 + xcd;   // y == xcd (mod 8): same-A-row blocks co-XCD
  }
  const long m0 = (long)by * 256;
  const long n0 = (long)bx * 256;
  if (mlim && m0 >= mlim[0]) return;
  const bf16* Bsel = (m0 >= msplit) ? Bt2 : Bt;
  const float* bsel = (m0 >= msplit) ? bias2 : bias;

  const int tid  = threadIdx.x;
  const int lane = tid & 63;
  const int wave = tid >> 6;
  const int wm = (wave >> 2) * 128;   // wave rows: 128 per wave_m
  const int wn = (wave & 3) * 64;     // wave cols: 64 per wave_n
  const int i16  = lane & 15;
  const int quad = lane >> 4;

  // staging: thread covers rows sr and sr+128, stored chunk sc = tid&3.
  const int sr = tid >> 2;                       // 0..127
  const int cA = (tid & 3) ^ ((sr >> 1) & 3);    // pre-swizzled global chunk
  const bf16* Ag0 = A    + (m0 + sr) * K + cA * 8;
  const bf16* Ag1 = A    + (m0 + 128 + sr) * K + cA * 8;
  const bf16* Bg0 = Bsel + (n0 + sr) * K + cA * 8;
  const bf16* Bg1 = Bsel + (n0 + 128 + sr) * K + cA * 8;
  const int ldst = tid << 4;                     // linear LDS dest (bytes)

  const int NK = K >> 5;                         // #ksub slots (K % 32 == 0)
  const int npre = NK < 3 ? NK : 3;
  for (int s = 0; s < npre; ++s) {
    char* as_ = sb + ((s & 3) << 14);
    char* bs_ = sb + 65536 + ((s & 3) << 14);
    gload16(Ag0 + s * 32, as_ + ldst);
    gload16(Ag1 + s * 32, as_ + 8192 + ldst);
    gload16(Bg0 + s * 32, bs_ + ldst);
    gload16(Bg1 + s * 32, bs_ + 8192 + ldst);
  }

  const int fc = (quad ^ ((i16 >> 1) & 3)) << 4;  // swizzled chunk byte offset
  f32x4 acc[8][4] = {};

  for (int s = 0; s < NK; ++s) {
    const char* as_ = sb + ((s & 3) << 14);
    const char* bs_ = sb + 65536 + ((s & 3) << 14);
    // slot entry: slot s's 4 loads are older than the 8 youngest (slots s+1,s+2)
    asm volatile("s_waitcnt vmcnt(8)" ::: "memory");
    __builtin_amdgcn_s_barrier();
    // ---- phase q0 ----
    bf16x8 a0[4], b0[4];
#pragma unroll
    for (int f = 0; f < 4; ++f)
      a0[f] = *(const bf16x8*)(as_ + (wm + f * 16 + i16) * 64 + fc);
#pragma unroll
    for (int g = 0; g < 4; ++g)
      b0[g] = *(const bf16x8*)(bs_ + (wn + g * 16 + i16) * 64 + fc);
    if (s + 3 < NK) {
      char* an = sb + (((s + 3) & 3) << 14);
      gload16(Ag0 + (s + 3) * 32, an + ldst);
      gload16(Ag1 + (s + 3) * 32, an + 8192 + ldst);
    }
    __builtin_amdgcn_s_barrier();
    asm volatile("s_waitcnt lgkmcnt(0)" ::: "memory");
    __builtin_amdgcn_sched_barrier(0);
    __builtin_amdgcn_s_setprio(1);
#pragma unroll
    for (int f = 0; f < 4; ++f)
#pragma unroll
      for (int g = 0; g < 4; ++g)
        acc[f][g] = __builtin_amdgcn_mfma_f32_16x16x32_bf16(a0[f], b0[g], acc[f][g], 0, 0, 0);
    __builtin_amdgcn_s_setprio(0);
    __builtin_amdgcn_s_barrier();
    // ---- phase q1 ----
    bf16x8 a1[4];
#pragma unroll
    for (int f = 0; f < 4; ++f)
      a1[f] = *(const bf16x8*)(as_ + (wm + (f + 4) * 16 + i16) * 64 + fc);
    if (s + 3 < NK) {
      char* bn = sb + 65536 + (((s + 3) & 3) << 14);
      gload16(Bg0 + (s + 3) * 32, bn + ldst);
      gload16(Bg1 + (s + 3) * 32, bn + 8192 + ldst);
    }
    __builtin_amdgcn_s_barrier();
    asm volatile("s_waitcnt lgkmcnt(0)" ::: "memory");
    __builtin_amdgcn_sched_barrier(0);
    __builtin_amdgcn_s_setprio(1);
#pragma unroll
    for (int f = 0; f < 4; ++f)
#pragma unroll
      for (int g = 0; g < 4; ++g)
        acc[f + 4][g] = __builtin_amdgcn_mfma_f32_16x16x32_bf16(a1[f], b0[g], acc[f + 4][g], 0, 0, 0);
    __builtin_amdgcn_s_setprio(0);
    // next slot-entry barrier closes this phase
  }

  if (!outf32) {
    // acc -> LDS (chunk-swizzled) -> 16B global stores
    __syncthreads();
    bf16* Cs = smem;   // 256 x 256 bf16 = 128 KB
#pragma unroll
    for (int g = 0; g < 4; ++g) {
      int col = wn + g * 16 + i16;
      int c8s = (col >> 3) ^ (quad << 1);
      int clo = col & 7;
      float bv = bsel[n0 + col];
#pragma unroll
      for (int f = 0; f < 8; ++f) {
#pragma unroll
        for (int r = 0; r < 4; ++r) {
          int row = wm + f * 16 + quad * 4 + r;   // (row>>2)&3 == quad
          float v = acc[f][g][r] + bv;
          if (act == 1) v = fmaxf(v, 0.0f);
          Cs[row * 256 + c8s * 8 + clo] = (bf16)v;
        }
      }
    }
    __syncthreads();
    bf16* Cg = (bf16*)C;
#pragma unroll
    for (int u = 0; u < 16; ++u) {
      int g = u * 512 + tid;
      int row = g >> 5, c8 = g & 31;
      int c8s = c8 ^ (((row >> 2) & 3) << 1);
      *(bf16x8*)(Cg + (m0 + row) * N + n0 + c8 * 8) =
          *(const bf16x8*)(Cs + row * 256 + c8s * 8);
    }
  } else {
#pragma unroll
    for (int f = 0; f < 8; ++f) {
#pragma unroll
      for (int g = 0; g < 4; ++g) {
        long col = n0 + wn + g * 16 + i16;
        float bv = bsel[col];
#pragma unroll
        for (int r = 0; r < 4; ++r) {
          long row = m0 + wm + f * 16 + quad * 4 + r;
          float v = acc[f][g][r] + bv;
          if (act == 1) v = fmaxf(v, 0.0f);
          else if (act == 2) v = tanhf(v);
          ((float*)C)[row * N + col] = v;
        }
      }
    }
  }
}

// ---------------- attention over compact rows (L keys, L queries) ----------------
__global__ __launch_bounds__(256, 8) void attn_kernel(
    const bf16* __restrict__ QKV, const int* __restrict__ fbase,
    const int* __restrict__ Lg, bf16* __restrict__ AO)
{
  const int bl  = blockIdx.x;
  const int tid = threadIdx.x;
  const int L   = Lg[bl];
  const long bs = fbase[bl];
  const bf16* qb = QKV + bs * 2304;
  __shared__ bf16 kx[12 * 768];       // chunk c8 of row s stored at chunk (c8 ^ (s&7))
  __shared__ float att[8][12][12];
  const int LC = L * 96;              // 16B chunks to stage
  for (int t = tid; t < LC; t += 256) {
    int s = t / 96, c8 = t - s * 96;
    *(bf16x8*)(kx + s * 768 + ((c8 ^ (s & 7)) << 3)) =
        *(const bf16x8*)(qb + (long)s * 2304 + 768 + (c8 << 3));
  }
  __syncthreads();
  const int LL = L * L;
  for (int t = tid; t < 8 * LL; t += 256) {
    int h = t / LL, r = t - h * LL, i = r / L, j = r - (r / L) * L;
    const bf16x8* q = (const bf16x8*)(qb + (long)i * 2304 + h * 96);
    const bf16* kr = kx + j * 768;
    const int cb = h * 12;
    const int jx = j & 7;
    float a = 0.0f;
#pragma unroll
    for (int d = 0; d < 12; ++d) {
      bf16x8 qa = q[d];
      bf16x8 ka = *(const bf16x8*)(kr + (((cb + d) ^ jx) << 3));
#pragma unroll
      for (int e = 0; e < 8; ++e) a += (float)qa[e] * (float)ka[e];
    }
    att[h][i][j] = a * 0.10206207261596575f;  // 1/sqrt(96)
  }
  __syncthreads();
  for (int t = tid; t < 8 * L; t += 256) {
    int h = t / L, i = t - (t / L) * L;
    float mx = -3e38f;
    for (int j = 0; j < L; ++j) mx = fmaxf(mx, att[h][i][j]);
    float sum = 0.0f;
    for (int j = 0; j < L; ++j) { float e = __expf(att[h][i][j] - mx); att[h][i][j] = e; sum += e; }
    float inv = 1.0f / sum;
    for (int j = 0; j < L; ++j) att[h][i][j] *= inv;
  }
  __syncthreads();
  for (int t = tid; t < LC; t += 256) {
    int i = t / 96, c8 = t - i * 96;
    int h = c8 / 12;
    const bf16* vp = qb + 1536 + (c8 << 3);
    float acc[8] = {};
    for (int j = 0; j < L; ++j) {
      float a = att[h][i][j];
      bf16x8 vv = *(const bf16x8*)(vp + (long)j * 2304);
#pragma unroll
      for (int e = 0; e < 8; ++e) acc[e] += a * (float)vv[e];
    }
    bf16x8 o;
#pragma unroll
    for (int e = 0; e < 8; ++e) o[e] = (bf16)acc[e];
    *(bf16x8*)(AO + (bs + i) * 768 + (c8 << 3)) = o;
  }
}

// ---------------- LN1: X = LN(gseq + WoO), compact rows ----------------
__global__ __launch_bounds__(256) void ln1_kernel(
    const bf16* __restrict__ WoO, const bf16* __restrict__ gseq,
    const float* __restrict__ gam, const float* __restrict__ bet,
    bf16* __restrict__ X, const int* __restrict__ meta)
{
  const long row = blockIdx.x;
  if (row >= meta[0]) return;
  const int tid = threadIdx.x;
  __shared__ float red[8];
  float v[3]; float s = 0.0f, ss = 0.0f;
#pragma unroll
  for (int u = 0; u < 3; ++u) {
    int c = tid + u * 256;
    float x = (float)WoO[row * 768 + c] + (float)gseq[row * 768 + c];
    v[u] = x; s += x; ss += x * x;
  }
  block_sum2(s, ss, red);
  float mu  = s * (1.0f / 768.0f);
  float var = ss * (1.0f / 768.0f) - mu * mu;
  float inv = 1.0f / sqrtf(var + 1e-5f);
#pragma unroll
  for (int u = 0; u < 3; ++u) {
    int c = tid + u * 256;
    X[row * 768 + c] = (bf16)((v[u] - mu) * inv * gam[c] + bet[c]);
  }
}

// ---------------- LN2 + mean pool + gate + mix -> out ----------------
__global__ __launch_bounds__(256) void ln2gate_kernel(
    const bf16* __restrict__ X, const bf16* __restrict__ FFo,
    const float* __restrict__ gam, const float* __restrict__ bet,
    const int* __restrict__ fbase, const int* __restrict__ Lg,
    const float* __restrict__ xdl, const float* __restrict__ Wg,
    const float* __restrict__ bg, float* __restrict__ out, int b0, int Bc)
{
  const int bl = blockIdx.x;
  const int tid = threadIdx.x;
  const int L = Lg[bl];
  const long bs = fbase[bl];
  __shared__ float red[8];
  __shared__ float red3[12];
  float p0 = 0.0f, p1 = 0.0f, p2 = 0.0f;
  for (int s = 0; s < L; ++s) {
    long row = bs + s;
    float v[3]; float sm = 0.0f, sq = 0.0f;
#pragma unroll
    for (int u = 0; u < 3; ++u) {
      int c = tid + u * 256;
      float x = (float)X[row * 768 + c] + (float)FFo[row * 768 + c];
      v[u] = x; sm += x; sq += x * x;
    }
    block_sum2(sm, sq, red);
    float mu  = sm * (1.0f / 768.0f);
    float var = sq * (1.0f / 768.0f) - mu * mu;
    float inv = 1.0f / sqrtf(var + 1e-5f);
    p0 += (v[0] - mu) * inv * gam[tid]       + bet[tid];
    p1 += (v[1] - mu) * inv * gam[tid + 256] + bet[tid + 256];
    p2 += (v[2] - mu) * inv * gam[tid + 512] + bet[tid + 512];
  }
  float dn = 1.0f / (float)L;
  p0 *= dn; p1 *= dn; p2 *= dn;
  const float* xd = xdl + (long)bl * 768;
  const float* xl = xdl + ((long)Bc + bl) * 768;
  float xd0 = xd[tid], xd1 = xd[tid + 256], xd2 = xd[tid + 512];
  float xl0 = xl[tid], xl1 = xl[tid + 256], xl2 = xl[tid + 512];
  float l0 = 0.0f, l1 = 0.0f, l2 = 0.0f;
#pragma unroll
  for (int r = 0; r < 3; ++r) {
    float lr = xd0 * Wg[tid * 3 + r] + xd1 * Wg[(tid + 256) * 3 + r] + xd2 * Wg[(tid + 512) * 3 + r]
             + xl0 * Wg[(768 + tid) * 3 + r] + xl1 * Wg[(1024 + tid) * 3 + r] + xl2 * Wg[(1280 + tid) * 3 + r]
             + p0 * Wg[(1536 + tid) * 3 + r] + p1 * Wg[(1792 + tid) * 3 + r] + p2 * Wg[(2048 + tid) * 3 + r];
    if (r == 0) l0 = lr; else if (r == 1) l1 = lr; else l2 = lr;
  }
#pragma unroll
  for (int o = 32; o; o >>= 1) {
    l0 += __shfl_xor(l0, o, 64);
    l1 += __shfl_xor(l1, o, 64);
    l2 += __shfl_xor(l2, o, 64);
  }
  if ((tid & 63) == 0) { int w = tid >> 6; red3[w * 3] = l0; red3[w * 3 + 1] = l1; red3[w * 3 + 2] = l2; }
  __syncthreads();
  l0 = red3[0] + red3[3] + red3[6] + red3[9]  + bg[0];
  l1 = red3[1] + red3[4] + red3[7] + red3[10] + bg[1];
  l2 = red3[2] + red3[5] + red3[8] + red3[11] + bg[2];
  float mx = fmaxf(l0, fmaxf(l1, l2));
  float e0 = __expf(l0 - mx), e1 = __expf(l1 - mx), e2 = __expf(l2 - mx);
  float inv = 1.0f / (e0 + e1 + e2);
  e0 *= inv; e1 *= inv; e2 *= inv;
  float* op = out + (long)(b0 + bl) * 768;
  op[tid]       = e0 * xd0 + e1 * xl0 + e2 * p0;
  op[tid + 256] = e0 * xd1 + e1 * xl1 + e2 * p1;
  op[tid + 512] = e0 * xd2 + e1 * xl2 + e2 * p2;
}

// ---------------- host ----------------
extern "C" void kernel_launch(void* const* d_in, const int* in_sizes, int n_in,
                              void* d_out, int out_size, void* d_ws, size_t ws_size,
                              hipStream_t stream) {
  const float* z    = (const float*)d_in[0];
  const float* buf  = (const float*)d_in[1];
  const int*   mask = (const int*)d_in[2];
  const int*   idxs = (const int*)d_in[3];
  const float* Wq = (const float*)d_in[4];  const float* bq = (const float*)d_in[5];
  const float* Wk = (const float*)d_in[6];  const float* bk = (const float*)d_in[7];
  const float* Wv = (const float*)d_in[8];  const float* bv = (const float*)d_in[9];
  const float* Wo = (const float*)d_in[10]; const float* bo = (const float*)d_in[11];
  const float* ln1g = (const float*)d_in[12]; const float* ln1b = (const float*)d_in[13];
  const float* W1 = (const float*)d_in[14]; const float* b1 = (const float*)d_in[15];
  const float* W2 = (const float*)d_in[16]; const float* b2 = (const float*)d_in[17];
  const float* ln2g = (const float*)d_in[18]; const float* ln2b = (const float*)d_in[19];
  const float* Wd = (const float*)d_in[20]; const float* bd = (const float*)d_in[21];
  const float* Wl = (const float*)d_in[22]; const float* blw = (const float*)d_in[23];
  const float* Wg = (const float*)d_in[24]; const float* bg = (const float*)d_in[25];
  float* out = (float*)d_out;
  (void)in_sizes; (void)n_in; (void)out_size;

  auto rnd = [](size_t x) { return (x + 255) & ~(size_t)255; };

  size_t fixed = 0;
  fixed += rnd((size_t)2304 * 768 * 2);
  fixed += rnd((size_t)768 * 768 * 2);
  fixed += rnd((size_t)2048 * 768 * 2);
  fixed += rnd((size_t)768 * 2048 * 2);
  fixed += rnd((size_t)768 * 768 * 2) * 2;
  fixed += rnd((size_t)2304 * 4) + 256 + 512 + 512;

  auto chunkBytes = [&](size_t bc) {
    return rnd((size_t)55296 * bc) + 3 * rnd((size_t)18432 * bc)
         + rnd((size_t)3072 * bc) + rnd((size_t)6144 * bc)
         + 3 * rnd((size_t)4 * bc);
  };
  int Bc = 8192;
  while (Bc > 1024 && fixed + chunkBytes(Bc) > ws_size) Bc >>= 1;

  size_t off = 0;
  auto alloc = [&](size_t n) { void* p = (char*)d_ws + off; off += rnd(n); return p; };
  bf16* Wqkv_t = (bf16*)alloc((size_t)2304 * 768 * 2);
  bf16* Wo_t   = (bf16*)alloc((size_t)768 * 768 * 2);
  bf16* W1_t   = (bf16*)alloc((size_t)2048 * 768 * 2);
  bf16* W2_t   = (bf16*)alloc((size_t)768 * 2048 * 2);
  bf16* Wd_t   = (bf16*)alloc((size_t)768 * 768 * 2);
  bf16* Wl_t   = (bf16*)alloc((size_t)768 * 768 * 2);
  float* bqkv  = (float*)alloc((size_t)2304 * 4);
  int*  meta   = (int*)alloc(256);
  int*  btot   = (int*)alloc(512);
  int*  boff   = (int*)alloc(512);
  bf16* P1 = (bf16*)alloc((size_t)55296 * Bc);  // QKV then FFa
  bf16* P2 = (bf16*)alloc((size_t)18432 * Bc);  // gseq then FFo
  bf16* P3 = (bf16*)alloc((size_t)18432 * Bc);  // AO then X
  bf16* P4 = (bf16*)alloc((size_t)18432 * Bc);  // WoO
  bf16* zl   = (bf16*)alloc((size_t)3072 * Bc); // [z ; lpool]
  float* xdl = (float*)alloc((size_t)6144 * Bc);
  int*  Lg    = (int*)alloc((size_t)4 * Bc);
  int*  lbase = (int*)alloc((size_t)4 * Bc);
  int*  fbase = (int*)alloc((size_t)4 * Bc);

  transpose_bf16<<<dim3(24, 24), 256, 0, stream>>>(Wq, Wqkv_t,                 768, 768);
  transpose_bf16<<<dim3(24, 24), 256, 0, stream>>>(Wk, Wqkv_t + 768 * 768,     768, 768);
  transpose_bf16<<<dim3(24, 24), 256, 0, stream>>>(Wv, Wqkv_t + 2 * 768 * 768, 768, 768);
  transpose_bf16<<<dim3(24, 24), 256, 0, stream>>>(Wo, Wo_t, 768, 768);
  transpose_bf16<<<dim3(64, 24), 256, 0, stream>>>(W1, W1_t, 768, 2048);
  transpose_bf16<<<dim3(24, 64), 256, 0, stream>>>(W2, W2_t, 2048, 768);
  transpose_bf16<<<dim3(24, 24), 256, 0, stream>>>(Wd, Wd_t, 768, 768);
  transpose_bf16<<<dim3(24, 24), 256, 0, stream>>>(Wl, Wl_t, 768, 768);
  pack3_kernel<<<9, 256, 0, stream>>>(bq, bk, bv, bqkv);

  const int BIG = 0x7fffffff;
  for (int b0 = 0; b0 < B_TOT; b0 += Bc) {
    const int Ycap = (12 * Bc) / 256;   // worst-case row tiles (mult of 8)
    scan1_kernel<<<Bc / 256, 256, 0, stream>>>(mask, Lg, lbase, btot, b0);
    scan2_kernel<<<1, 64, 0, stream>>>(btot, boff, meta, Bc / 256);
    prep_kernel<<<Bc, 256, 0, stream>>>(z, buf, mask, idxs, lbase, boff, fbase, P2, zl, b0, Bc);
    // xdl = tanh([z;lpool] @ [Wd|Wl] + [bd|bl])  (row-split B)
    gemm256<<<dim3(3, (2 * Bc) / 256), 512, 0, stream>>>(zl, Wd_t, bd, xdl, 768, 768, 2, 1, nullptr, Bc, Wl_t, blw);
    // QKV = gseq @ Wqkv
    gemm256<<<dim3(9, Ycap), 512, 0, stream>>>(P2, Wqkv_t, bqkv, P1, 768, 2304, 0, 0, meta, BIG, nullptr, nullptr);
    attn_kernel<<<Bc, 256, 0, stream>>>(P1, fbase, Lg, P3);
    // WoO = AO @ Wo
    gemm256<<<dim3(3, Ycap), 512, 0, stream>>>(P3, Wo_t, bo, P4, 768, 768, 0, 0, meta, BIG, nullptr, nullptr);
    // X = LN1(gseq + WoO)
    ln1_kernel<<<12 * Bc, 256, 0, stream>>>(P4, P2, ln1g, ln1b, P3, meta);
    // FFa = relu(X @ W1)
    gemm256<<<dim3(8, Ycap), 512, 0, stream>>>(P3, W1_t, b1, P1, 768, 2048, 1, 0, meta, BIG, nullptr, nullptr);
    // FFo = FFa @ W2
    gemm256<<<dim3(3, Ycap), 512, 0, stream>>>(P1, W2_t, b2, P2, 2048, 768, 0, 0, meta, BIG, nullptr, nullptr);
    // LN2 + pool + gate + mix
    ln2gate_kernel<<<Bc, 256, 0, stream>>>(P3, P2, ln2g, ln2b, fbase, Lg, xdl, Wg, bg, out, b0, Bc);
  }
}

// Round 3
// 1472.304 us; speedup vs baseline: 1.0417x; 1.0417x over previous
//
#include <hip/hip_runtime.h>
#include <cstdint>
#include <cstddef>

typedef __bf16 bf16;
typedef __attribute__((ext_vector_type(8))) __bf16 bf16x8;
typedef __attribute__((ext_vector_type(4))) __bf16 bf16x4;
typedef __attribute__((ext_vector_type(4))) float f32x4;

#define B_TOT 8192

// ---------------- async global->LDS (16B per lane) ----------------
__device__ __forceinline__ void gload16(const void* g, void* l) {
  __builtin_amdgcn_global_load_lds(
      (__attribute__((address_space(1))) void*)g,
      (__attribute__((address_space(3))) void*)l, 16, 0, 0);
}

__device__ __forceinline__ bf16x4 cvt4(f32x4 v) {
  bf16x4 o; o[0] = (bf16)v[0]; o[1] = (bf16)v[1]; o[2] = (bf16)v[2]; o[3] = (bf16)v[3];
  return o;
}

// ---------------- scan phase 1: per-block exclusive scan of L ----------------
__global__ __launch_bounds__(256) void scan1_kernel(
    const int* __restrict__ mask, int* __restrict__ Lg, int* __restrict__ lbase,
    int* __restrict__ btot, int b0)
{
  __shared__ int ts[256];
  const int t = threadIdx.x;
  const int b = blockIdx.x * 256 + t;
  const int* mp = mask + (long)(b0 + b) * 12;
  int nv = 0;
#pragma unroll
  for (int p = 0; p < 12; ++p) nv += (mp[p] != 0);
  int L = (nv < 11 ? nv : 11) + 1;
  ts[t] = L;
  __syncthreads();
  for (int o = 1; o < 256; o <<= 1) {
    int v = (t >= o) ? ts[t - o] : 0;
    __syncthreads();
    ts[t] += v;
    __syncthreads();
  }
  Lg[b] = L;
  lbase[b] = ts[t] - L;
  if (t == 255) btot[blockIdx.x] = ts[255];
}

// ---------------- scan phase 2: scan of block totals (nb <= 32, trivial) ----------------
__global__ __launch_bounds__(64) void scan2_kernel(
    const int* __restrict__ btot, int* __restrict__ boff, int* __restrict__ meta, int nb)
{
  if (threadIdx.x == 0) {
    int acc = 0;
    for (int i = 0; i < nb; ++i) { int v = btot[i]; boff[i] = acc; acc += v; }
    meta[0] = acc;
  }
}

// ---------------- prep: compact age-sorted gather; zl = [z ; lpool]; fbase ----------------
// v2: float4 loads / bf16x4 stores, 192 threads (768/4 chunks), one pass.
__global__ __launch_bounds__(192) void prep_kernel(
    const float* __restrict__ z, const float* __restrict__ buf,
    const int* __restrict__ mask, const int* __restrict__ idxs,
    const int* __restrict__ lbase, const int* __restrict__ boff,
    int* __restrict__ fbase, bf16* __restrict__ gseq,
    bf16* __restrict__ zl, int b0, int Bc)
{
  const int bl = blockIdx.x;
  const int b  = b0 + bl;
  __shared__ int ord[12];
  __shared__ int s_nv;
  if (threadIdx.x == 0) {
    int id = idxs[b];
    int nv = 0;
    for (int a = 11; a >= 0; --a) {   // ages descending -> oldest first
      int pos = id - a; if (pos < 0) pos += 12;
      if (mask[b * 12 + pos]) ord[nv++] = pos;
    }
    s_nv = nv;
  }
  const long bs = (long)lbase[bl] + boff[bl >> 8];
  if (threadIdx.x == 0) fbase[bl] = (int)bs;
  __syncthreads();
  const int nv = s_nv;
  const int hg = (nv < 11 ? nv : 11);   // valid rows = hg + 1 (last is zero-row or z)
  const int hl = (nv < 4 ? nv : 4);
  const float ld = 1.0f / (float)(hl + 1);

  const int c4 = threadIdx.x;           // 0..191, 16B chunk per thread
  const f32x4* z4   = (const f32x4*)z;
  const f32x4* buf4 = (const f32x4*)buf;
  bf16x4* gseq4 = (bf16x4*)gseq;
  bf16x4* zl4   = (bf16x4*)zl;

  f32x4 zv = z4[(long)b * 192 + c4];
  zl4[(long)bl * 192 + c4] = cvt4(zv);
  f32x4 ls = {0.0f, 0.0f, 0.0f, 0.0f};
  for (int s = 0; s < hg; ++s) {
    f32x4 v = buf4[((long)b * 12 + ord[s]) * 192 + c4];
    gseq4[(bs + s) * 192 + c4] = cvt4(v);
    if (s < hl) ls += v;
  }
  f32x4 zero = {0.0f, 0.0f, 0.0f, 0.0f};
  gseq4[(bs + hg) * 192 + c4] = cvt4(hg == 11 ? zv : zero);
  if (nv >= 4) ls += zv;
  zl4[((long)Bc + bl) * 192 + c4] = cvt4(ls * ld);
}

// ---------------- weight transpose f32(K,N) -> bf16(N,K) ----------------
__global__ __launch_bounds__(256) void transpose_bf16(
    const float* __restrict__ W, bf16* __restrict__ Wt, int K, int N)
{
  __shared__ float tile[32][33];
  int bn = blockIdx.x * 32;
  int bk = blockIdx.y * 32;
  int tx = threadIdx.x & 31;
  int ty0 = threadIdx.x >> 5;
  for (int ty = ty0; ty < 32; ty += 8)
    tile[ty][tx] = W[(long)(bk + ty) * N + bn + tx];
  __syncthreads();
  for (int ty = ty0; ty < 32; ty += 8)
    Wt[(long)(bn + ty) * K + bk + tx] = (bf16)tile[tx][ty];
}

__global__ __launch_bounds__(256) void pack3_kernel(
    const float* __restrict__ a, const float* __restrict__ b,
    const float* __restrict__ c, float* __restrict__ out)
{
  int t = blockIdx.x * blockDim.x + threadIdx.x;
  if (t < 768) out[t] = a[t];
  else if (t < 1536) out[t] = b[t - 768];
  else if (t < 2304) out[t] = c[t - 1536];
}

// ---------------- MFMA GEMM: C(M,N) = A(M,K) @ Bt(N,K)^T + bias ----------------
// 128x128 tile, BK=64, XCD-aware y-swizzle, early-exit past mlim[0] rows,
// optional row-split B (rows >= msplit use Bt2/bias2).
// LDS chunk swizzle: LDS(r, cpos) holds global chunk cpos ^ (r&7).
__global__ __launch_bounds__(256, 2) void gemm_bt(
    const bf16* __restrict__ A, const bf16* __restrict__ Bt,
    const float* __restrict__ bias, void* __restrict__ C,
    int K, int N, int act, int outf32,
    const int* __restrict__ mlim, int msplit,
    const bf16* __restrict__ Bt2, const float* __restrict__ bias2)
{
  __shared__ __align__(16) bf16 smem[2 * 128 * 64];
  bf16* As = smem;
  bf16* Bs = smem + 128 * 64;
  int gx = gridDim.x, gy = gridDim.y;
  int bx = blockIdx.x, by = blockIdx.y;
  if ((gy & 7) == 0) {
    int l = bx + gx * by;
    int xcd = l & 7, slot = l >> 3;
    bx = slot % gx;
    by = (slot / gx) * 8 + xcd;   // y == xcd (mod 8): same-A-row blocks co-XCD
  }
  const long m0 = (long)by * 128;
  const long n0 = (long)bx * 128;
  if (mlim && m0 >= mlim[0]) return;
  const bf16* Bsel = (m0 >= msplit) ? Bt2 : Bt;
  const float* bsel = (m0 >= msplit) ? bias2 : bias;

  const int tid  = threadIdx.x;
  const int wave = tid >> 6;
  const int lane = tid & 63;
  const int wm = (wave >> 1) * 64;
  const int wn = (wave & 1) * 64;
  const int i16  = lane & 15;
  const int quad = lane >> 4;
  const int l8 = lane >> 3;
  const int c7 = lane & 7;

  // staging: wave w stages rows [w*32, w*32+32) of both tiles; 4 segs of 8 rows
  const int csrc = c7 ^ l8;   // source chunk for swizzled LDS layout
  const bf16* Ag[4]; const bf16* Bg[4];
  bf16* Al[4]; bf16* Bl[4];
#pragma unroll
  for (int u = 0; u < 4; ++u) {
    int r = wave * 32 + u * 8 + l8;
    Ag[u] = A    + (m0 + r) * K + csrc * 8;
    Bg[u] = Bsel + (n0 + r) * K + csrc * 8;
    Al[u] = As + (wave * 32 + u * 8) * 64 + lane * 8;
    Bl[u] = Bs + (wave * 32 + u * 8) * 64 + lane * 8;
  }

  f32x4 acc[4][4] = {};

  for (int kt = 0; kt < K; kt += 64) {
    __syncthreads();
#pragma unroll
    for (int u = 0; u < 4; ++u) {
      gload16(Ag[u] + kt, Al[u]);
      gload16(Bg[u] + kt, Bl[u]);
    }
    __syncthreads();
#pragma unroll
    for (int s = 0; s < 2; ++s) {
      const int cofs = ((s << 2) | quad) ^ c7;   // frag rows have r&7 == c7
      bf16x8 af[4], bfr[4];
#pragma unroll
      for (int i = 0; i < 4; ++i)
        af[i] = *(const bf16x8*)(As + (wm + i * 16 + i16) * 64 + cofs * 8);
#pragma unroll
      for (int j = 0; j < 4; ++j)
        bfr[j] = *(const bf16x8*)(Bs + (wn + j * 16 + i16) * 64 + cofs * 8);
#pragma unroll
      for (int i = 0; i < 4; ++i)
#pragma unroll
        for (int j = 0; j < 4; ++j)
          acc[i][j] = __builtin_amdgcn_mfma_f32_16x16x32_bf16(af[i], bfr[j], acc[i][j], 0, 0, 0);
    }
  }

  if (!outf32) {
    // vectorized bf16 epilogue: acc -> LDS (chunk-swizzled) -> 16B global stores
    __syncthreads();
    bf16* Cs = smem;   // 128 x 128 bf16 = 32 KB
#pragma unroll
    for (int j = 0; j < 4; ++j) {
      int col = wn + j * 16 + i16;
      int c8s = (col >> 3) ^ (quad << 1);
      int clo = col & 7;
      float bv = bsel[n0 + col];
#pragma unroll
      for (int i = 0; i < 4; ++i) {
#pragma unroll
        for (int r = 0; r < 4; ++r) {
          int row = wm + i * 16 + quad * 4 + r;   // (row>>2)&3 == quad
          float v = acc[i][j][r] + bv;
          if (act == 1) v = fmaxf(v, 0.0f);
          Cs[row * 128 + c8s * 8 + clo] = (bf16)v;
        }
      }
    }
    __syncthreads();
    bf16* Cg = (bf16*)C;
#pragma unroll
    for (int u = 0; u < 8; ++u) {
      int g = u * 256 + tid;
      int row = g >> 4, c8 = g & 15;
      int c8s = c8 ^ (((row >> 2) & 3) << 1);
      *(bf16x8*)(Cg + (m0 + row) * N + n0 + c8 * 8) =
          *(const bf16x8*)(Cs + row * 128 + c8s * 8);
    }
  } else {
#pragma unroll
    for (int i = 0; i < 4; ++i) {
#pragma unroll
      for (int j = 0; j < 4; ++j) {
        long col = n0 + wn + j * 16 + i16;
        float bv = bsel[col];
#pragma unroll
        for (int r = 0; r < 4; ++r) {
          long row = m0 + wm + i * 16 + quad * 4 + r;
          float v = acc[i][j][r] + bv;
          if (act == 1) v = fmaxf(v, 0.0f);
          else if (act == 2) v = tanhf(v);
          ((float*)C)[row * N + col] = v;
        }
      }
    }
  }
}

// ---------------- attention over compact rows (L keys, L queries) ----------------
__global__ __launch_bounds__(256, 8) void attn_kernel(
    const bf16* __restrict__ QKV, const int* __restrict__ fbase,
    const int* __restrict__ Lg, bf16* __restrict__ AO)
{
  const int bl  = blockIdx.x;
  const int tid = threadIdx.x;
  const int L   = Lg[bl];
  const long bs = fbase[bl];
  const bf16* qb = QKV + bs * 2304;
  __shared__ bf16 kx[12 * 768];       // chunk c8 of row s stored at chunk (c8 ^ (s&7))
  __shared__ float att[8][12][12];
  const int LC = L * 96;              // 16B chunks to stage
  for (int t = tid; t < LC; t += 256) {
    int s = t / 96, c8 = t - s * 96;
    *(bf16x8*)(kx + s * 768 + ((c8 ^ (s & 7)) << 3)) =
        *(const bf16x8*)(qb + (long)s * 2304 + 768 + (c8 << 3));
  }
  __syncthreads();
  const int LL = L * L;
  for (int t = tid; t < 8 * LL; t += 256) {
    int h = t / LL, r = t - h * LL, i = r / L, j = r - (r / L) * L;
    const bf16x8* q = (const bf16x8*)(qb + (long)i * 2304 + h * 96);
    const bf16* kr = kx + j * 768;
    const int cb = h * 12;
    const int jx = j & 7;
    float a = 0.0f;
#pragma unroll
    for (int d = 0; d < 12; ++d) {
      bf16x8 qa = q[d];
      bf16x8 ka = *(const bf16x8*)(kr + (((cb + d) ^ jx) << 3));
#pragma unroll
      for (int e = 0; e < 8; ++e) a += (float)qa[e] * (float)ka[e];
    }
    att[h][i][j] = a * 0.10206207261596575f;  // 1/sqrt(96)
  }
  __syncthreads();
  for (int t = tid; t < 8 * L; t += 256) {
    int h = t / L, i = t - (t / L) * L;
    float mx = -3e38f;
    for (int j = 0; j < L; ++j) mx = fmaxf(mx, att[h][i][j]);
    float sum = 0.0f;
    for (int j = 0; j < L; ++j) { float e = __expf(att[h][i][j] - mx); att[h][i][j] = e; sum += e; }
    float inv = 1.0f / sum;
    for (int j = 0; j < L; ++j) att[h][i][j] *= inv;
  }
  __syncthreads();
  for (int t = tid; t < LC; t += 256) {
    int i = t / 96, c8 = t - i * 96;
    int h = c8 / 12;
    const bf16* vp = qb + 1536 + (c8 << 3);
    float acc[8] = {};
    for (int j = 0; j < L; ++j) {
      float a = att[h][i][j];
      bf16x8 vv = *(const bf16x8*)(vp + (long)j * 2304);
#pragma unroll
      for (int e = 0; e < 8; ++e) acc[e] += a * (float)vv[e];
    }
    bf16x8 o;
#pragma unroll
    for (int e = 0; e < 8; ++e) o[e] = (bf16)acc[e];
    *(bf16x8*)(AO + (bs + i) * 768 + (c8 << 3)) = o;
  }
}

// ---------------- LN1: X = LN(gseq + WoO), wave-per-row, barrier-free ----------------
// 4 rows/block (one per wave); lane covers 16B chunks {lane, 64+lane(lane<32)} of the
// 96-chunk row; shfl-only reductions; bf16x8 loads/stores.
__global__ __launch_bounds__(256) void ln1_kernel(
    const bf16* __restrict__ WoO, const bf16* __restrict__ gseq,
    const float* __restrict__ gam, const float* __restrict__ bet,
    bf16* __restrict__ X, const int* __restrict__ meta)
{
  const int wave = threadIdx.x >> 6;
  const int lane = threadIdx.x & 63;
  const long row = (long)blockIdx.x * 4 + wave;
  if (row >= meta[0]) return;
  const bf16x8* Wv = (const bf16x8*)WoO;
  const bf16x8* Gv = (const bf16x8*)gseq;
  const long r96 = row * 96;
  const int c0 = lane;
  const int c1 = 64 + lane;
  float va[8], vb[8];
  float sm = 0.0f, sq = 0.0f;
  {
    bf16x8 wa = Wv[r96 + c0], ga = Gv[r96 + c0];
#pragma unroll
    for (int e = 0; e < 8; ++e) {
      float x = (float)wa[e] + (float)ga[e];
      va[e] = x; sm += x; sq += x * x;
    }
  }
  if (lane < 32) {
    bf16x8 wb = Wv[r96 + c1], gb = Gv[r96 + c1];
#pragma unroll
    for (int e = 0; e < 8; ++e) {
      float x = (float)wb[e] + (float)gb[e];
      vb[e] = x; sm += x; sq += x * x;
    }
  }
#pragma unroll
  for (int o = 32; o; o >>= 1) {
    sm += __shfl_xor(sm, o, 64);
    sq += __shfl_xor(sq, o, 64);
  }
  float mu  = sm * (1.0f / 768.0f);
  float var = sq * (1.0f / 768.0f) - mu * mu;
  float inv = 1.0f / sqrtf(var + 1e-5f);
  {
    bf16x8 o;
#pragma unroll
    for (int e = 0; e < 8; ++e)
      o[e] = (bf16)((va[e] - mu) * inv * gam[c0 * 8 + e] + bet[c0 * 8 + e]);
    ((bf16x8*)X)[r96 + c0] = o;
  }
  if (lane < 32) {
    bf16x8 o;
#pragma unroll
    for (int e = 0; e < 8; ++e)
      o[e] = (bf16)((vb[e] - mu) * inv * gam[c1 * 8 + e] + bet[c1 * 8 + e]);
    ((bf16x8*)X)[r96 + c1] = o;
  }
}

// ---------------- LN2 + mean pool + gate + mix -> out ----------------
// v2: wave-per-row LN+pool (shfl-only, no barriers in the row loop), bf16x8 loads,
// per-wave pooled partials combined once through LDS, then the gate tail.
__global__ __launch_bounds__(256) void ln2gate_kernel(
    const bf16* __restrict__ X, const bf16* __restrict__ FFo,
    const float* __restrict__ gam, const float* __restrict__ bet,
    const int* __restrict__ fbase, const int* __restrict__ Lg,
    const float* __restrict__ xdl, const float* __restrict__ Wg,
    const float* __restrict__ bg, float* __restrict__ out, int b0, int Bc)
{
  const int bl = blockIdx.x;
  const int tid = threadIdx.x;
  const int wave = tid >> 6;
  const int lane = tid & 63;
  const int L = Lg[bl];
  const long bs = fbase[bl];
  __shared__ float pool[4][768];
  __shared__ float red3[12];

  const int c0 = lane;
  const int c1 = 64 + lane;
  const bf16x8* Xv = (const bf16x8*)X;
  const bf16x8* Fv = (const bf16x8*)FFo;
  float ga[8], be[8], gb[8], bb[8];
#pragma unroll
  for (int e = 0; e < 8; ++e) { ga[e] = gam[c0 * 8 + e]; be[e] = bet[c0 * 8 + e]; }
  if (lane < 32) {
#pragma unroll
    for (int e = 0; e < 8; ++e) { gb[e] = gam[c1 * 8 + e]; bb[e] = bet[c1 * 8 + e]; }
  }
  float pa[8] = {}, pb[8] = {};
  for (int s = wave; s < L; s += 4) {
    const long r96 = (bs + s) * 96;
    float va[8], vb[8];
    float sm = 0.0f, sq = 0.0f;
    {
      bf16x8 xa = Xv[r96 + c0], fa = Fv[r96 + c0];
#pragma unroll
      for (int e = 0; e < 8; ++e) {
        float x = (float)xa[e] + (float)fa[e];
        va[e] = x; sm += x; sq += x * x;
      }
    }
    if (lane < 32) {
      bf16x8 xb = Xv[r96 + c1], fb = Fv[r96 + c1];
#pragma unroll
      for (int e = 0; e < 8; ++e) {
        float x = (float)xb[e] + (float)fb[e];
        vb[e] = x; sm += x; sq += x * x;
      }
    }
#pragma unroll
    for (int o = 32; o; o >>= 1) {
      sm += __shfl_xor(sm, o, 64);
      sq += __shfl_xor(sq, o, 64);
    }
    float mu  = sm * (1.0f / 768.0f);
    float var = sq * (1.0f / 768.0f) - mu * mu;
    float inv = 1.0f / sqrtf(var + 1e-5f);
#pragma unroll
    for (int e = 0; e < 8; ++e) pa[e] += (va[e] - mu) * inv * ga[e] + be[e];
    if (lane < 32) {
#pragma unroll
      for (int e = 0; e < 8; ++e) pb[e] += (vb[e] - mu) * inv * gb[e] + bb[e];
    }
  }
#pragma unroll
  for (int e = 0; e < 8; ++e) pool[wave][c0 * 8 + e] = pa[e];
  if (lane < 32) {
#pragma unroll
    for (int e = 0; e < 8; ++e) pool[wave][c1 * 8 + e] = pb[e];
  }
  __syncthreads();

  float p0 = pool[0][tid]       + pool[1][tid]       + pool[2][tid]       + pool[3][tid];
  float p1 = pool[0][tid + 256] + pool[1][tid + 256] + pool[2][tid + 256] + pool[3][tid + 256];
  float p2 = pool[0][tid + 512] + pool[1][tid + 512] + pool[2][tid + 512] + pool[3][tid + 512];
  float dn = 1.0f / (float)L;
  p0 *= dn; p1 *= dn; p2 *= dn;
  const float* xd = xdl + (long)bl * 768;
  const float* xl = xdl + ((long)Bc + bl) * 768;
  float xd0 = xd[tid], xd1 = xd[tid + 256], xd2 = xd[tid + 512];
  float xl0 = xl[tid], xl1 = xl[tid + 256], xl2 = xl[tid + 512];
  float l0 = 0.0f, l1 = 0.0f, l2 = 0.0f;
#pragma unroll
  for (int r = 0; r < 3; ++r) {
    float lr = xd0 * Wg[tid * 3 + r] + xd1 * Wg[(tid + 256) * 3 + r] + xd2 * Wg[(tid + 512) * 3 + r]
             + xl0 * Wg[(768 + tid) * 3 + r] + xl1 * Wg[(1024 + tid) * 3 + r] + xl2 * Wg[(1280 + tid) * 3 + r]
             + p0 * Wg[(1536 + tid) * 3 + r] + p1 * Wg[(1792 + tid) * 3 + r] + p2 * Wg[(2048 + tid) * 3 + r];
    if (r == 0) l0 = lr; else if (r == 1) l1 = lr; else l2 = lr;
  }
#pragma unroll
  for (int o = 32; o; o >>= 1) {
    l0 += __shfl_xor(l0, o, 64);
    l1 += __shfl_xor(l1, o, 64);
    l2 += __shfl_xor(l2, o, 64);
  }
  if ((tid & 63) == 0) { int w = tid >> 6; red3[w * 3] = l0; red3[w * 3 + 1] = l1; red3[w * 3 + 2] = l2; }
  __syncthreads();
  l0 = red3[0] + red3[3] + red3[6] + red3[9]  + bg[0];
  l1 = red3[1] + red3[4] + red3[7] + red3[10] + bg[1];
  l2 = red3[2] + red3[5] + red3[8] + red3[11] + bg[2];
  float mx = fmaxf(l0, fmaxf(l1, l2));
  float e0 = __expf(l0 - mx), e1 = __expf(l1 - mx), e2 = __expf(l2 - mx);
  float inv = 1.0f / (e0 + e1 + e2);
  e0 *= inv; e1 *= inv; e2 *= inv;
  float* op = out + (long)(b0 + bl) * 768;
  op[tid]       = e0 * xd0 + e1 * xl0 + e2 * p0;
  op[tid + 256] = e0 * xd1 + e1 * xl1 + e2 * p1;
  op[tid + 512] = e0 * xd2 + e1 * xl2 + e2 * p2;
}

// ---------------- host ----------------
extern "C" void kernel_launch(void* const* d_in, const int* in_sizes, int n_in,
                              void* d_out, int out_size, void* d_ws, size_t ws_size,
                              hipStream_t stream) {
  const float* z    = (const float*)d_in[0];
  const float* buf  = (const float*)d_in[1];
  const int*   mask = (const int*)d_in[2];
  const int*   idxs = (const int*)d_in[3];
  const float* Wq = (const float*)d_in[4];  const float* bq = (const float*)d_in[5];
  const float* Wk = (const float*)d_in[6];  const float* bk = (const float*)d_in[7];
  const float* Wv = (const float*)d_in[8];  const float* bv = (const float*)d_in[9];
  const float* Wo = (const float*)d_in[10]; const float* bo = (const float*)d_in[11];
  const float* ln1g = (const float*)d_in[12]; const float* ln1b = (const float*)d_in[13];
  const float* W1 = (const float*)d_in[14]; const float* b1 = (const float*)d_in[15];
  const float* W2 = (const float*)d_in[16]; const float* b2 = (const float*)d_in[17];
  const float* ln2g = (const float*)d_in[18]; const float* ln2b = (const float*)d_in[19];
  const float* Wd = (const float*)d_in[20]; const float* bd = (const float*)d_in[21];
  const float* Wl = (const float*)d_in[22]; const float* blw = (const float*)d_in[23];
  const float* Wg = (const float*)d_in[24]; const float* bg = (const float*)d_in[25];
  float* out = (float*)d_out;
  (void)in_sizes; (void)n_in; (void)out_size;

  auto rnd = [](size_t x) { return (x + 255) & ~(size_t)255; };

  size_t fixed = 0;
  fixed += rnd((size_t)2304 * 768 * 2);
  fixed += rnd((size_t)768 * 768 * 2);
  fixed += rnd((size_t)2048 * 768 * 2);
  fixed += rnd((size_t)768 * 2048 * 2);
  fixed += rnd((size_t)768 * 768 * 2) * 2;
  fixed += rnd((size_t)2304 * 4) + 256 + 512 + 512;

  auto chunkBytes = [&](size_t bc) {
    return rnd((size_t)55296 * bc) + 3 * rnd((size_t)18432 * bc)
         + rnd((size_t)3072 * bc) + rnd((size_t)6144 * bc)
         + 3 * rnd((size_t)4 * bc);
  };
  int Bc = 8192;
  while (Bc > 1024 && fixed + chunkBytes(Bc) > ws_size) Bc >>= 1;

  size_t off = 0;
  auto alloc = [&](size_t n) { void* p = (char*)d_ws + off; off += rnd(n); return p; };
  bf16* Wqkv_t = (bf16*)alloc((size_t)2304 * 768 * 2);
  bf16* Wo_t   = (bf16*)alloc((size_t)768 * 768 * 2);
  bf16* W1_t   = (bf16*)alloc((size_t)2048 * 768 * 2);
  bf16* W2_t   = (bf16*)alloc((size_t)768 * 2048 * 2);
  bf16* Wd_t   = (bf16*)alloc((size_t)768 * 768 * 2);
  bf16* Wl_t   = (bf16*)alloc((size_t)768 * 768 * 2);
  float* bqkv  = (float*)alloc((size_t)2304 * 4);
  int*  meta   = (int*)alloc(256);
  int*  btot   = (int*)alloc(512);
  int*  boff   = (int*)alloc(512);
  bf16* P1 = (bf16*)alloc((size_t)55296 * Bc);  // QKV then FFa
  bf16* P2 = (bf16*)alloc((size_t)18432 * Bc);  // gseq then FFo
  bf16* P3 = (bf16*)alloc((size_t)18432 * Bc);  // AO then X
  bf16* P4 = (bf16*)alloc((size_t)18432 * Bc);  // WoO
  bf16* zl   = (bf16*)alloc((size_t)3072 * Bc); // [z ; lpool]
  float* xdl = (float*)alloc((size_t)6144 * Bc);
  int*  Lg    = (int*)alloc((size_t)4 * Bc);
  int*  lbase = (int*)alloc((size_t)4 * Bc);
  int*  fbase = (int*)alloc((size_t)4 * Bc);

  transpose_bf16<<<dim3(24, 24), 256, 0, stream>>>(Wq, Wqkv_t,                 768, 768);
  transpose_bf16<<<dim3(24, 24), 256, 0, stream>>>(Wk, Wqkv_t + 768 * 768,     768, 768);
  transpose_bf16<<<dim3(24, 24), 256, 0, stream>>>(Wv, Wqkv_t + 2 * 768 * 768, 768, 768);
  transpose_bf16<<<dim3(24, 24), 256, 0, stream>>>(Wo, Wo_t, 768, 768);
  transpose_bf16<<<dim3(64, 24), 256, 0, stream>>>(W1, W1_t, 768, 2048);
  transpose_bf16<<<dim3(24, 64), 256, 0, stream>>>(W2, W2_t, 2048, 768);
  transpose_bf16<<<dim3(24, 24), 256, 0, stream>>>(Wd, Wd_t, 768, 768);
  transpose_bf16<<<dim3(24, 24), 256, 0, stream>>>(Wl, Wl_t, 768, 768);
  pack3_kernel<<<9, 256, 0, stream>>>(bq, bk, bv, bqkv);

  const int BIG = 0x7fffffff;
  for (int b0 = 0; b0 < B_TOT; b0 += Bc) {
    const int Ycap = (12 * Bc) / 128;   // worst-case row tiles
    scan1_kernel<<<Bc / 256, 256, 0, stream>>>(mask, Lg, lbase, btot, b0);
    scan2_kernel<<<1, 64, 0, stream>>>(btot, boff, meta, Bc / 256);
    prep_kernel<<<Bc, 192, 0, stream>>>(z, buf, mask, idxs, lbase, boff, fbase, P2, zl, b0, Bc);
    // xdl = tanh([z;lpool] @ [Wd|Wl] + [bd|bl])  (row-split B)
    gemm_bt<<<dim3(6, (2 * Bc) / 128), 256, 0, stream>>>(zl, Wd_t, bd, xdl, 768, 768, 2, 1, nullptr, Bc, Wl_t, blw);
    // QKV = gseq @ Wqkv
    gemm_bt<<<dim3(18, Ycap), 256, 0, stream>>>(P2, Wqkv_t, bqkv, P1, 768, 2304, 0, 0, meta, BIG, nullptr, nullptr);
    attn_kernel<<<Bc, 256, 0, stream>>>(P1, fbase, Lg, P3);
    // WoO = AO @ Wo
    gemm_bt<<<dim3(6, Ycap), 256, 0, stream>>>(P3, Wo_t, bo, P4, 768, 768, 0, 0, meta, BIG, nullptr, nullptr);
    // X = LN1(gseq + WoO)
    ln1_kernel<<<3 * Bc, 256, 0, stream>>>(P4, P2, ln1g, ln1b, P3, meta);
    // FFa = relu(X @ W1)
    gemm_bt<<<dim3(16, Ycap), 256, 0, stream>>>(P3, W1_t, b1, P1, 768, 2048, 1, 0, meta, BIG, nullptr, nullptr);
    // FFo = FFa @ W2
    gemm_bt<<<dim3(6, Ycap), 256, 0, stream>>>(P1, W2_t, b2, P2, 2048, 768, 0, 0, meta, BIG, nullptr, nullptr);
    // LN2 + pool + gate + mix
    ln2gate_kernel<<<Bc, 256, 0, stream>>>(P3, P2, ln2g, ln2b, fbase, Lg, xdl, Wg, bg, out, b0, Bc);
  }
}